// Round 5
// baseline (2412.928 us; speedup 1.0000x reference)
//
#include <hip/hip_runtime.h>

// ---------------------------------------------------------------------------
// Swin block on MI355X. B=8, H=W=128, C=256, NH=8, HD=32, WS=8, SS=4, N=64,
// NW=256, tokens M=131072, HID=1024.
// ws (256 MiB):
//   phase1: qkvb [0,192M) | winb [192,256M)
//   phase2 (post-attn): yb [0,64M) | h1b [64,192M) | projout [128,192M) (dead
//           before h1b written) | fc1wb/fc2wb [192,256M) (after proj reads winb)
// d_out doubles as scratch until resid_ln2: qkvwb [0,384K), rpbm [512K,1M),
//   mconv [1M,1M+64K), projwb [1.25M,+128K)
// ---------------------------------------------------------------------------

typedef unsigned short u16;
typedef unsigned int   u32;
typedef __attribute__((ext_vector_type(4))) int   ivec4;
typedef __attribute__((ext_vector_type(4))) float fvec4;
typedef __attribute__((ext_vector_type(8))) short svec8;
typedef __attribute__((ext_vector_type(4))) unsigned short usvec4;
typedef __attribute__((ext_vector_type(4))) float floatx4;

#define SCALE_Q 0.17677669529663687f

__device__ __forceinline__ u16 f2bf(float f) {
  union { float f; u32 u; } v; v.f = f;
  u32 r = v.u + 0x7FFFu + ((v.u >> 16) & 1u);
  return (u16)(r >> 16);
}
__device__ __forceinline__ float bf2f(u16 h) {
  union { u32 u; float f; } v; v.u = ((u32)h) << 16; return v.f;
}

// ---------------------------------------------------------------------------
// LN1: wave per token (4 tokens/block), float4/lane, shuffle-only reduce.
// SHIFT=1: token order = shifted window partition (gather read of x).
// ---------------------------------------------------------------------------
template<int SHIFT>
__global__ __launch_bounds__(256)
void ln_kernel(const float* __restrict__ x, const float* __restrict__ g,
               const float* __restrict__ b, u16* __restrict__ out)
{
  const int t    = blockIdx.x * 4 + (threadIdx.x >> 6);
  const int lane = threadIdx.x & 63;
  const int c    = lane * 4;
  size_t src;
  if constexpr (SHIFT) {
    int w  = t >> 6, tk = t & 63;
    int bi = w >> 8, wi = w & 255;
    int hr = ((wi >> 4) << 3) + (tk >> 3);
    int wr = ((wi & 15) << 3) + (tk & 7);
    int ho = (hr + 4) & 127, wo = (wr + 4) & 127;
    src = ((size_t)bi * 16384 + (size_t)ho * 128 + wo) * 256 + c;
  } else {
    src = (size_t)t * 256 + c;
  }
  fvec4 v = *(const fvec4*)(x + src);
  float s  = v.x + v.y + v.z + v.w;
  float s2 = v.x * v.x + v.y * v.y + v.z * v.z + v.w * v.w;
  #pragma unroll
  for (int o = 32; o > 0; o >>= 1) { s += __shfl_xor(s, o); s2 += __shfl_xor(s2, o); }
  float mu  = s * (1.0f / 256.0f);
  float var = s2 * (1.0f / 256.0f) - mu * mu;
  float inv = rsqrtf(var + 1e-5f);
  fvec4 gg = *(const fvec4*)(g + c);
  fvec4 bb = *(const fvec4*)(b + c);
  usvec4 o4;
  o4[0] = f2bf((v.x - mu) * inv * gg.x + bb.x);
  o4[1] = f2bf((v.y - mu) * inv * gg.y + bb.y);
  o4[2] = f2bf((v.z - mu) * inv * gg.z + bb.z);
  o4[3] = f2bf((v.w - mu) * inv * gg.w + bb.w);
  *(usvec4*)(out + (size_t)t * 256 + c) = o4;
}

// ---------------------------------------------------------------------------
// resid_ln2: wave per pixel P (row-major). x2 = x + permute(proj_out);
// write x2 (f32, d_out) and LN2(x2) (bf16, yb).
// ---------------------------------------------------------------------------
__global__ __launch_bounds__(256)
void resid_ln2(const float* __restrict__ x, const u16* __restrict__ projout,
               const float* __restrict__ g, const float* __restrict__ b,
               float* __restrict__ x2, u16* __restrict__ yb)
{
  const int P    = blockIdx.x * 4 + (threadIdx.x >> 6);
  const int lane = threadIdx.x & 63;
  const int c    = lane * 4;
  const int bi = P >> 14, ho = (P >> 7) & 127, wo = P & 127;
  const int hr = (ho + 124) & 127, wr = (wo + 124) & 127;
  const int token = (((bi << 8) + ((hr >> 3) << 4) + (wr >> 3)) << 6)
                    + ((hr & 7) << 3) + (wr & 7);
  fvec4 xv = *(const fvec4*)(x + (size_t)P * 256 + c);
  usvec4 pv = *(const usvec4*)(projout + (size_t)token * 256 + c);
  fvec4 v;
  v.x = xv.x + bf2f(pv[0]); v.y = xv.y + bf2f(pv[1]);
  v.z = xv.z + bf2f(pv[2]); v.w = xv.w + bf2f(pv[3]);
  *(fvec4*)(x2 + (size_t)P * 256 + c) = v;
  float s  = v.x + v.y + v.z + v.w;
  float s2 = v.x * v.x + v.y * v.y + v.z * v.z + v.w * v.w;
  #pragma unroll
  for (int o = 32; o > 0; o >>= 1) { s += __shfl_xor(s, o); s2 += __shfl_xor(s2, o); }
  float mu  = s * (1.0f / 256.0f);
  float var = s2 * (1.0f / 256.0f) - mu * mu;
  float inv = rsqrtf(var + 1e-5f);
  fvec4 gg = *(const fvec4*)(g + c);
  fvec4 bb = *(const fvec4*)(b + c);
  usvec4 o4;
  o4[0] = f2bf((v.x - mu) * inv * gg.x + bb.x);
  o4[1] = f2bf((v.y - mu) * inv * gg.y + bb.y);
  o4[2] = f2bf((v.z - mu) * inv * gg.z + bb.z);
  o4[3] = f2bf((v.w - mu) * inv * gg.w + bb.w);
  *(usvec4*)(yb + (size_t)P * 256 + c) = o4;
}

// ---------------------------------------------------------------------------
// Small setup kernels
// ---------------------------------------------------------------------------
__global__ __launch_bounds__(256)
void cvt_kernel(const float* __restrict__ src, u16* __restrict__ dst, int n) {
  int i = (blockIdx.x * 256 + threadIdx.x) * 4;
  if (i < n) {
    fvec4 v = *(const fvec4*)(src + i);
    usvec4 o; o[0] = f2bf(v.x); o[1] = f2bf(v.y); o[2] = f2bf(v.z); o[3] = f2bf(v.w);
    *(usvec4*)(dst + i) = o;
  }
}

// rpbm[cls][h][n][m] = rpb[relidx(n,m)][h] + pe_b[h] + mask(cls,n,m)
__global__ __launch_bounds__(256)
void rpbm_kernel(const float* __restrict__ rpb, const float* __restrict__ pe_b,
                 float* __restrict__ out) {
  int idx = blockIdx.x * 256 + threadIdx.x;          // 131072
  int m = idx & 63, n = (idx >> 6) & 63, hh = (idx >> 12) & 7, cls = idx >> 15;
  int dy = (n >> 3) - (m >> 3) + 7, dx = (n & 7) - (m & 7) + 7;
  float v = rpb[(dy * 15 + dx) * 8 + hh] + pe_b[hh];
  int lastR = cls >> 1, lastC = cls & 1;
  int rn = lastR ? (((n >> 3) < 4) ? 1 : 2) : 0;
  int cn = lastC ? (((n & 7) < 4) ? 1 : 2) : 0;
  int rm = lastR ? (((m >> 3) < 4) ? 1 : 2) : 0;
  int cm = lastC ? (((m & 7) < 4) ? 1 : 2) : 0;
  if (rn * 3 + cn != rm * 3 + cm) v -= 100.0f;
  out[idx] = v;
}

// mconv[h][n][nn] = (n==nn) + (|nn-n|<=7 ? pe_w[h][nn-n+7] : 0), bf16
__global__ __launch_bounds__(256)
void mconv_kernel(const float* __restrict__ pe_w, u16* __restrict__ out) {
  int idx = blockIdx.x * 256 + threadIdx.x;          // 32768
  int nn = idx & 63, n = (idx >> 6) & 63, hh = idx >> 12;
  int d = nn - n;
  float v = (d == 0) ? 1.0f : 0.0f;
  if (d >= -7 && d <= 7) v += pe_w[hh * 15 + d + 7];
  out[idx] = f2bf(v);
}

// ---------------------------------------------------------------------------
// sgemm: weight-stationary streaming GEMM. C[M,N] = A[M,K]bf16 * W[N,K]bf16^T.
// Block = 512 thr (8 waves). Each block owns a 128-wide N-strip; the W strip
// (128 x 256 bf16 = 64 KB, XOR-swizzled 16B units -> 2-way max conflicts) is
// staged into LDS once (per K-chunk), then the block streams NSPB M-strips of
// 128 rows with NO barriers: A frags global->reg, MFMA vs LDS W, store.
// Wave wv owns rows [strip + wv*16, +16), all 8 n-tiles (acc = 32 VGPR).
// KCHUNKS=4 (fc2, K=1024): 4 chunks, 2 barriers/chunk, persistent acc[NSPB].
// Block decode: same-M blocks land on same XCD (A-panel L2 reuse).
// EPI: 0 qkv (+bias, scale q) | 1 proj (+bias) | 2 fc1 (+bias, exact gelu)
//      3 fc2 (+bias + residual f32 in d_out)
// ---------------------------------------------------------------------------
template<int EPI, int KCHUNKS, int NSPB>
__global__ __launch_bounds__(512, 4)
void sgemm(const u16* __restrict__ A, const u16* __restrict__ Bw,
           const float* __restrict__ bias, u16* __restrict__ outb, float* outf,
           const float* extra, int N, int row0, int gy)
{
  constexpr int K = KCHUNKS * 256;
  __shared__ __align__(16) u16 Ws[128 * 256];       // 64 KB, swizzled

  const int tid  = threadIdx.x;
  const int lane = tid & 63;
  const int wv   = tid >> 6;            // 0..7
  const int lo   = lane & 15, hi = lane >> 4;

  // decode: xcd-major so same-m blocks share an XCD (A L2 reuse across strips)
  const int hb  = blockIdx.x;
  const int xcd = hb & 7;
  const int j   = hb >> 3;
  const int ns  = j % gy;
  const int mb  = (j / gy) * 8 + xcd;
  const int n0  = ns * 128;
  const size_t mbase = (size_t)mb * (128 * NSPB);

  // swizzled ds_read base offsets (per kk), computed once
  int bo[8];
  #pragma unroll
  for (int kk = 0; kk < 8; ++kk) {
    int u  = kk * 4 + hi;
    int up = (u & 24) | ((u ^ lo) & 7);
    bo[kk] = lo * 256 + up * 8;
  }

  const int wr = tid >> 2, wq = tid & 3;   // staging: row, quarter

  auto epilogue = [&](floatx4 (&a)[8], size_t ms0) {
    #pragma unroll
    for (int nt = 0; nt < 8; ++nt) {
      int c = n0 + nt * 16 + lo;
      float bv = bias[c];
      #pragma unroll
      for (int jj = 0; jj < 4; ++jj) {
        size_t r = ms0 + hi * 4 + jj;
        float v = a[nt][jj] + bv;
        if constexpr (EPI == 0) {
          if (c < 256) v *= SCALE_Q;
          outb[r * N + c] = f2bf(v);
        } else if constexpr (EPI == 1) {
          outb[r * N + c] = f2bf(v);
        } else if constexpr (EPI == 2) {
          float gv = 0.5f * v * (1.0f + erff(v * 0.70710678118654752f));
          outb[r * N + c] = f2bf(gv);
        } else {
          size_t o = (size_t)(row0 + r) * N + c;
          outf[o] = extra[o] + v;
        }
      }
    }
  };

  if constexpr (KCHUNKS == 1) {
    { // stage W strip once
      const u16* src = Bw + (size_t)(n0 + wr) * K;
      #pragma unroll
      for (int i = 0; i < 8; ++i) {
        int u  = wq * 8 + i;
        int up = (u & 24) | ((u ^ wr) & 7);
        *(ivec4*)&Ws[wr * 256 + up * 8] = *(const ivec4*)(src + u * 8);
      }
    }
    __syncthreads();
    #pragma unroll 1
    for (int s = 0; s < NSPB; ++s) {
      const size_t ms0 = mbase + s * 128 + wv * 16;
      const u16* arow = A + (ms0 + lo) * (size_t)K;
      svec8 af[8];
      #pragma unroll
      for (int kk = 0; kk < 8; ++kk)
        af[kk] = *(const svec8*)(arow + kk * 32 + hi * 8);
      floatx4 acc[8] = {};
      #pragma unroll
      for (int nt = 0; nt < 8; ++nt) {
        #pragma unroll
        for (int kk = 0; kk < 8; ++kk) {
          svec8 bfr = *(const svec8*)&Ws[nt * 4096 + bo[kk]];
          acc[nt] = __builtin_amdgcn_mfma_f32_16x16x32_bf16(af[kk], bfr, acc[nt], 0, 0, 0);
        }
      }
      epilogue(acc, ms0);
    }
  } else {
    floatx4 acc[NSPB][8] = {};
    for (int c = 0; c < KCHUNKS; ++c) {
      if (c) __syncthreads();              // all reads of prev chunk done
      { // stage chunk c
        const u16* src = Bw + (size_t)(n0 + wr) * K + c * 256;
        #pragma unroll
        for (int i = 0; i < 8; ++i) {
          int u  = wq * 8 + i;
          int up = (u & 24) | ((u ^ wr) & 7);
          *(ivec4*)&Ws[wr * 256 + up * 8] = *(const ivec4*)(src + u * 8);
        }
      }
      __syncthreads();
      #pragma unroll
      for (int s = 0; s < NSPB; ++s) {
        const size_t ms0 = mbase + s * 128 + wv * 16;
        const u16* arow = A + (ms0 + lo) * (size_t)K + c * 256;
        svec8 af[8];
        #pragma unroll
        for (int kk = 0; kk < 8; ++kk)
          af[kk] = *(const svec8*)(arow + kk * 32 + hi * 8);
        #pragma unroll
        for (int nt = 0; nt < 8; ++nt) {
          #pragma unroll
          for (int kk = 0; kk < 8; ++kk) {
            svec8 bfr = *(const svec8*)&Ws[nt * 4096 + bo[kk]];
            acc[s][nt] = __builtin_amdgcn_mfma_f32_16x16x32_bf16(af[kk], bfr, acc[s][nt], 0, 0, 0);
          }
        }
      }
    }
    #pragma unroll
    for (int s = 0; s < NSPB; ++s)
      epilogue(acc[s], mbase + s * 128 + wv * 16);
  }
}

// ---------------------------------------------------------------------------
// Attention: one block per (window, head), 4 waves; wave wv owns queries
// [wv*16, wv*16+16). Logits = (I+T) @ S_bf16 (MFMA, acc init = rpbm which
// folds rpb + pe_b + shift mask). In-register softmax. PV via LDS.
// ---------------------------------------------------------------------------
__global__ __launch_bounds__(256)
void attn2(const u16* __restrict__ qkv, const float* __restrict__ rpbm,
           const u16* __restrict__ mconv, u16* __restrict__ outb)
{
  __shared__ __align__(16) u16 Ks[64 * 40];
  __shared__ __align__(16) u16 Vt[32 * 72];
  __shared__ __align__(16) u16 ST[64 * 72];
  __shared__ __align__(16) u16 Pm[64 * 72];

  const int tid  = threadIdx.x;
  const int lane = tid & 63, wv = tid >> 6;
  const int lo   = lane & 15, hi = lane >> 4;
  const int wId  = blockIdx.x >> 3;
  const int h    = blockIdx.x & 7;
  const int wi   = wId & 255;
  const int cls  = (((wi >> 4) == 15) ? 2 : 0) + (((wi & 15) == 15) ? 1 : 0);
  const int m0   = wv * 16;

  { // stage k and V^T
    int r = tid >> 2, ch = tid & 3;
    const size_t base = (size_t)(wId * 64 + r) * 768 + h * 32 + ch * 8;
    *(ivec4*)&Ks[r * 40 + ch * 8] = *(const ivec4*)(qkv + base + 256);
    ivec4 vv = *(const ivec4*)(qkv + base + 512);
    const u16* pv = (const u16*)&vv;
    #pragma unroll
    for (int e = 0; e < 8; ++e) Vt[(ch * 8 + e) * 72 + r] = pv[e];
  }
  __syncthreads();

  { // QK^T (K=32): A = q rows (global), B = k rows (LDS). Write S^T bf16.
    svec8 qa = *(const svec8*)(qkv + (size_t)(wId * 64 + m0 + lo) * 768 + h * 32 + hi * 8);
    floatx4 z = {0.f, 0.f, 0.f, 0.f};
    #pragma unroll
    for (int nb = 0; nb < 4; ++nb) {
      svec8 kb = *(const svec8*)&Ks[(nb * 16 + lo) * 40 + hi * 8];
      floatx4 s = __builtin_amdgcn_mfma_f32_16x16x32_bf16(qa, kb, z, 0, 0, 0);
      #pragma unroll
      for (int jp = 0; jp < 2; ++jp) {
        u32 pk = (u32)f2bf(s[jp * 2]) | ((u32)f2bf(s[jp * 2 + 1]) << 16);
        *(u32*)&ST[(nb * 16 + lo) * 72 + m0 + hi * 4 + jp * 2] = pk;
      }
    }
  }
  __syncthreads();

  floatx4 acc[4];
  { // conv-MFMA: L = (I+T) @ S, acc init = rpbm
    const float* rb = rpbm + (size_t)(cls * 8 + h) * 4096;
    #pragma unroll
    for (int nb = 0; nb < 4; ++nb)
      #pragma unroll
      for (int j = 0; j < 4; ++j)
        acc[nb][j] = rb[(m0 + hi * 4 + j) * 64 + nb * 16 + lo];
    svec8 mf0 = *(const svec8*)(mconv + ((h * 64 + m0 + lo) * 64 + hi * 8));
    svec8 mf1 = *(const svec8*)(mconv + ((h * 64 + m0 + lo) * 64 + 32 + hi * 8));
    #pragma unroll
    for (int nb = 0; nb < 4; ++nb) {
      svec8 st0 = *(const svec8*)&ST[(nb * 16 + lo) * 72 + hi * 8];
      svec8 st1 = *(const svec8*)&ST[(nb * 16 + lo) * 72 + 32 + hi * 8];
      acc[nb] = __builtin_amdgcn_mfma_f32_16x16x32_bf16(mf0, st0, acc[nb], 0, 0, 0);
      acc[nb] = __builtin_amdgcn_mfma_f32_16x16x32_bf16(mf1, st1, acc[nb], 0, 0, 0);
    }
  }

  { // in-register softmax over keys
    float ev[4][4], inv[4];
    #pragma unroll
    for (int j = 0; j < 4; ++j) {
      float m_ = fmaxf(fmaxf(acc[0][j], acc[1][j]), fmaxf(acc[2][j], acc[3][j]));
      m_ = fmaxf(m_, __shfl_xor(m_, 1)); m_ = fmaxf(m_, __shfl_xor(m_, 2));
      m_ = fmaxf(m_, __shfl_xor(m_, 4)); m_ = fmaxf(m_, __shfl_xor(m_, 8));
      #pragma unroll
      for (int nb = 0; nb < 4; ++nb) ev[nb][j] = __expf(acc[nb][j] - m_);
      float s_ = ev[0][j] + ev[1][j] + ev[2][j] + ev[3][j];
      s_ += __shfl_xor(s_, 1); s_ += __shfl_xor(s_, 2);
      s_ += __shfl_xor(s_, 4); s_ += __shfl_xor(s_, 8);
      inv[j] = __builtin_amdgcn_rcpf(s_);
    }
    #pragma unroll
    for (int nb = 0; nb < 4; ++nb)
      #pragma unroll
      for (int j = 0; j < 4; ++j)
        Pm[(m0 + hi * 4 + j) * 72 + nb * 16 + lo] = f2bf(ev[nb][j] * inv[j]);
  }
  __syncthreads();

  { // PV
    floatx4 oacc[2] = {};
    #pragma unroll
    for (int ks = 0; ks < 2; ++ks) {
      svec8 pa = *(const svec8*)&Pm[(m0 + lo) * 72 + ks * 32 + hi * 8];
      #pragma unroll
      for (int nb = 0; nb < 2; ++nb) {
        svec8 vb = *(const svec8*)&Vt[(nb * 16 + lo) * 72 + ks * 32 + hi * 8];
        oacc[nb] = __builtin_amdgcn_mfma_f32_16x16x32_bf16(pa, vb, oacc[nb], 0, 0, 0);
      }
    }
    #pragma unroll
    for (int nb = 0; nb < 2; ++nb)
      #pragma unroll
      for (int j = 0; j < 4; ++j)
        outb[(size_t)(wId * 64 + m0 + hi * 4 + j) * 256 + h * 32 + nb * 16 + lo] = f2bf(oacc[nb][j]);
  }
}

// ---------------------------------------------------------------------------
extern "C" void kernel_launch(void* const* d_in, const int* in_sizes, int n_in,
                              void* d_out, int out_size, void* d_ws, size_t ws_size,
                              hipStream_t stream)
{
  const float* x      = (const float*)d_in[0];
  const float* n1g    = (const float*)d_in[1];
  const float* n1b    = (const float*)d_in[2];
  const float* qkv_w  = (const float*)d_in[3];
  const float* qkv_b  = (const float*)d_in[4];
  const float* rpb    = (const float*)d_in[5];
  const float* pe_w   = (const float*)d_in[6];
  const float* pe_b   = (const float*)d_in[7];
  const float* proj_w = (const float*)d_in[8];
  const float* proj_b = (const float*)d_in[9];
  const float* n2g    = (const float*)d_in[10];
  const float* n2b    = (const float*)d_in[11];
  const float* fc1_w  = (const float*)d_in[12];
  const float* fc1_b  = (const float*)d_in[13];
  const float* fc2_w  = (const float*)d_in[14];
  const float* fc2_b  = (const float*)d_in[15];
  float* outf = (float*)d_out;

  char* ws = (char*)d_ws;
  u16* qkvb    = (u16*)ws;                          // [0,192M) phase1
  u16* winb    = (u16*)(ws + (192ull << 20));       // [192,256M) phase1
  u16* yb      = (u16*)ws;                          // [0,64M)   phase2
  u16* h1b     = (u16*)(ws + (64ull << 20));        // [64,192M) phase2
  u16* projoutb= (u16*)(ws + (128ull << 20));       // [128,192M) (dead before h1 use)
  u16* fc1wb   = (u16*)(ws + (192ull << 20));       // 512K (after proj reads winb)
  u16* fc2wb   = (u16*)(ws + (192ull << 20) + (1ull << 19));

  // d_out scratch (dead until resid_ln2)
  u16*   qkvwb  = (u16*)d_out;                              // 384K
  float* rpbmT  = (float*)((char*)d_out + (1ull << 19));    // 512K
  u16*   mconvT = (u16*)((char*)d_out + (1ull << 20));      // 64K
  u16*   projwb = (u16*)((char*)d_out + (1ull << 20) + (1ull << 18)); // 128K

  // setup
  cvt_kernel<<<192, 256, 0, stream>>>(qkv_w, qkvwb, 196608);
  rpbm_kernel<<<512, 256, 0, stream>>>(rpb, pe_b, rpbmT);
  mconv_kernel<<<128, 256, 0, stream>>>(pe_w, mconvT);
  cvt_kernel<<<64, 256, 0, stream>>>(proj_w, projwb, 65536);

  // 1) LN1 + shift + window partition
  ln_kernel<1><<<32768, 256, 0, stream>>>(x, n1g, n1b, winb);
  // 2) QKV GEMM: N=768 (6 strips), M-strips 1024, NSPB=4 -> MB=256, NB=1536
  sgemm<0, 1, 4><<<1536, 512, 0, stream>>>(winb, qkvwb, qkv_b, qkvb, nullptr, nullptr, 768, 0, 6);
  // 3) attention -> winb (overwrites LN1 output)
  attn2<<<16384, 256, 0, stream>>>(qkvb, rpbmT, mconvT, winb);
  // 4) proj GEMM -> projout bf16: N=256 (2 strips), NSPB=4 -> NB=512
  sgemm<1, 1, 4><<<512, 512, 0, stream>>>(winb, projwb, proj_b, projoutb, nullptr, nullptr, 256, 0, 2);
  // 4b) convert fc weights into [192,256M) (winb now dead)
  cvt_kernel<<<256, 256, 0, stream>>>(fc1_w, fc1wb, 262144);
  cvt_kernel<<<256, 256, 0, stream>>>(fc2_w, fc2wb, 262144);
  // 5) fused unshift+residual+LN2: x2 -> d_out, yb -> ws
  resid_ln2<<<32768, 256, 0, stream>>>(x, projoutb, n2g, n2b, outf, yb);
  // 6) MLP in two M-halves (h1 = 128 MiB in [64,192M))
  for (int half = 0; half < 2; ++half) {
    int r0 = half * 65536;
    // fc1: N=1024 (8 strips), M-strips 512, NSPB=4 -> MB=128, NB=1024
    sgemm<2, 1, 4><<<1024, 512, 0, stream>>>(yb + (size_t)r0 * 256, fc1wb, fc1_b, h1b, nullptr, nullptr, 1024, 0, 8);
    // fc2: N=256 (2 strips), K=1024 (4 chunks), NSPB=2 -> MB=256, NB=512
    sgemm<3, 4, 2><<<512, 512, 0, stream>>>(h1b, fc2wb, fc2_b, nullptr, outf, outf, 256, r0, 2);
  }
}

// Round 6
// 1534.939 us; speedup vs baseline: 1.5720x; 1.5720x over previous
//
#include <hip/hip_runtime.h>

// ---------------------------------------------------------------------------
// Swin block on MI355X. B=8, H=W=128, C=256, NH=8, HD=32, WS=8, SS=4, N=64,
// NW=256, tokens M=131072, HID=1024.
// ws (256 MiB):
//   phase1: qkvb [0,192M) | winb [192,256M)
//   phase2 (post-attn): yb [0,64M) | projout [64,128M) | fc1wb/fc2wb [192,256M)
// d_out doubles as scratch until resid_ln2: qkvwb [0,384K), rpbm [512K,1M),
//   mconv [1M,1M+64K), projwb [1.25M,+128K)
// ---------------------------------------------------------------------------

typedef unsigned short u16;
typedef unsigned int   u32;
typedef __attribute__((ext_vector_type(4))) int   ivec4;
typedef __attribute__((ext_vector_type(4))) float fvec4;
typedef __attribute__((ext_vector_type(8))) short svec8;
typedef __attribute__((ext_vector_type(4))) unsigned short usvec4;
typedef __attribute__((ext_vector_type(4))) float floatx4;

#define SCALE_Q 0.17677669529663687f

__device__ __forceinline__ u16 f2bf(float f) {
  union { float f; u32 u; } v; v.f = f;
  u32 r = v.u + 0x7FFFu + ((v.u >> 16) & 1u);
  return (u16)(r >> 16);
}
__device__ __forceinline__ float bf2f(u16 h) {
  union { u32 u; float f; } v; v.u = ((u32)h) << 16; return v.f;
}

__device__ __forceinline__ void async_copy16(const u16* g, u16* l) {
  __builtin_amdgcn_global_load_lds(
      (const __attribute__((address_space(1))) u32*)g,
      (__attribute__((address_space(3))) u32*)l, 16, 0, 0);
}

// ---------------------------------------------------------------------------
// LN1: wave per token (4 tokens/block), float4/lane, shuffle-only reduce.
// SHIFT=1: token order = shifted window partition (gather read of x).
// ---------------------------------------------------------------------------
template<int SHIFT>
__global__ __launch_bounds__(256)
void ln_kernel(const float* __restrict__ x, const float* __restrict__ g,
               const float* __restrict__ b, u16* __restrict__ out)
{
  const int t    = blockIdx.x * 4 + (threadIdx.x >> 6);
  const int lane = threadIdx.x & 63;
  const int c    = lane * 4;
  size_t src;
  if constexpr (SHIFT) {
    int w  = t >> 6, tk = t & 63;
    int bi = w >> 8, wi = w & 255;
    int hr = ((wi >> 4) << 3) + (tk >> 3);
    int wr = ((wi & 15) << 3) + (tk & 7);
    int ho = (hr + 4) & 127, wo = (wr + 4) & 127;
    src = ((size_t)bi * 16384 + (size_t)ho * 128 + wo) * 256 + c;
  } else {
    src = (size_t)t * 256 + c;
  }
  fvec4 v = *(const fvec4*)(x + src);
  float s  = v.x + v.y + v.z + v.w;
  float s2 = v.x * v.x + v.y * v.y + v.z * v.z + v.w * v.w;
  #pragma unroll
  for (int o = 32; o > 0; o >>= 1) { s += __shfl_xor(s, o); s2 += __shfl_xor(s2, o); }
  float mu  = s * (1.0f / 256.0f);
  float var = s2 * (1.0f / 256.0f) - mu * mu;
  float inv = rsqrtf(var + 1e-5f);
  fvec4 gg = *(const fvec4*)(g + c);
  fvec4 bb = *(const fvec4*)(b + c);
  usvec4 o4;
  o4[0] = f2bf((v.x - mu) * inv * gg.x + bb.x);
  o4[1] = f2bf((v.y - mu) * inv * gg.y + bb.y);
  o4[2] = f2bf((v.z - mu) * inv * gg.z + bb.z);
  o4[3] = f2bf((v.w - mu) * inv * gg.w + bb.w);
  *(usvec4*)(out + (size_t)t * 256 + c) = o4;
}

// ---------------------------------------------------------------------------
// resid_ln2: wave per pixel P (row-major). x2 = x + permute(proj_out);
// write x2 (f32, d_out) and LN2(x2) (bf16, yb).
// ---------------------------------------------------------------------------
__global__ __launch_bounds__(256)
void resid_ln2(const float* __restrict__ x, const u16* __restrict__ projout,
               const float* __restrict__ g, const float* __restrict__ b,
               float* __restrict__ x2, u16* __restrict__ yb)
{
  const int P    = blockIdx.x * 4 + (threadIdx.x >> 6);
  const int lane = threadIdx.x & 63;
  const int c    = lane * 4;
  const int bi = P >> 14, ho = (P >> 7) & 127, wo = P & 127;
  const int hr = (ho + 124) & 127, wr = (wo + 124) & 127;
  const int token = (((bi << 8) + ((hr >> 3) << 4) + (wr >> 3)) << 6)
                    + ((hr & 7) << 3) + (wr & 7);
  fvec4 xv = *(const fvec4*)(x + (size_t)P * 256 + c);
  usvec4 pv = *(const usvec4*)(projout + (size_t)token * 256 + c);
  fvec4 v;
  v.x = xv.x + bf2f(pv[0]); v.y = xv.y + bf2f(pv[1]);
  v.z = xv.z + bf2f(pv[2]); v.w = xv.w + bf2f(pv[3]);
  *(fvec4*)(x2 + (size_t)P * 256 + c) = v;
  float s  = v.x + v.y + v.z + v.w;
  float s2 = v.x * v.x + v.y * v.y + v.z * v.z + v.w * v.w;
  #pragma unroll
  for (int o = 32; o > 0; o >>= 1) { s += __shfl_xor(s, o); s2 += __shfl_xor(s2, o); }
  float mu  = s * (1.0f / 256.0f);
  float var = s2 * (1.0f / 256.0f) - mu * mu;
  float inv = rsqrtf(var + 1e-5f);
  fvec4 gg = *(const fvec4*)(g + c);
  fvec4 bb = *(const fvec4*)(b + c);
  usvec4 o4;
  o4[0] = f2bf((v.x - mu) * inv * gg.x + bb.x);
  o4[1] = f2bf((v.y - mu) * inv * gg.y + bb.y);
  o4[2] = f2bf((v.z - mu) * inv * gg.z + bb.z);
  o4[3] = f2bf((v.w - mu) * inv * gg.w + bb.w);
  *(usvec4*)(yb + (size_t)P * 256 + c) = o4;
}

// ---------------------------------------------------------------------------
// Small setup kernels
// ---------------------------------------------------------------------------
__global__ __launch_bounds__(256)
void cvt_kernel(const float* __restrict__ src, u16* __restrict__ dst, int n) {
  int i = (blockIdx.x * 256 + threadIdx.x) * 4;
  if (i < n) {
    fvec4 v = *(const fvec4*)(src + i);
    usvec4 o; o[0] = f2bf(v.x); o[1] = f2bf(v.y); o[2] = f2bf(v.z); o[3] = f2bf(v.w);
    *(usvec4*)(dst + i) = o;
  }
}

// rpbm[cls][h][n][m] = rpb[relidx(n,m)][h] + pe_b[h] + mask(cls,n,m)
__global__ __launch_bounds__(256)
void rpbm_kernel(const float* __restrict__ rpb, const float* __restrict__ pe_b,
                 float* __restrict__ out) {
  int idx = blockIdx.x * 256 + threadIdx.x;          // 131072
  int m = idx & 63, n = (idx >> 6) & 63, hh = (idx >> 12) & 7, cls = idx >> 15;
  int dy = (n >> 3) - (m >> 3) + 7, dx = (n & 7) - (m & 7) + 7;
  float v = rpb[(dy * 15 + dx) * 8 + hh] + pe_b[hh];
  int lastR = cls >> 1, lastC = cls & 1;
  int rn = lastR ? (((n >> 3) < 4) ? 1 : 2) : 0;
  int cn = lastC ? (((n & 7) < 4) ? 1 : 2) : 0;
  int rm = lastR ? (((m >> 3) < 4) ? 1 : 2) : 0;
  int cm = lastC ? (((m & 7) < 4) ? 1 : 2) : 0;
  if (rn * 3 + cn != rm * 3 + cm) v -= 100.0f;
  out[idx] = v;
}

// mconv[h][n][nn] = (n==nn) + (|nn-n|<=7 ? pe_w[h][nn-n+7] : 0), bf16
__global__ __launch_bounds__(256)
void mconv_kernel(const float* __restrict__ pe_w, u16* __restrict__ out) {
  int idx = blockIdx.x * 256 + threadIdx.x;          // 32768
  int nn = idx & 63, n = (idx >> 6) & 63, hh = idx >> 12;
  int d = nn - n;
  float v = (d == 0) ? 1.0f : 0.0f;
  if (d >= -7 && d <= 7) v += pe_w[hh * 15 + d + 7];
  out[idx] = f2bf(v);
}

// ---------------------------------------------------------------------------
// GEMM v4 (round-4 proven): C[M,N] = A[M,K]bf16 * W[N,K]bf16^T. 128x128 tile,
// BK=32, 8 waves, wave tile 32x64, double-buffered LDS, one barrier/K-step,
// global_load_lds width16, XCD-aware bijective swizzle (grids % 8 == 0).
// EPI: 0 qkv (+bias, scale q, bf16) | 1 proj (+bias, bf16 linear)
// ---------------------------------------------------------------------------
template<int EPI>
__global__ __launch_bounds__(512, 4)
void gemm4(const u16* __restrict__ A, const u16* __restrict__ Bw,
           const float* __restrict__ bias, u16* outb, float* outf,
           const float* __restrict__ extra, int N, int K, int row0)
{
  __shared__ __align__(16) u16 As[2][128 * 32];
  __shared__ __align__(16) u16 Bs[2][128 * 32];
  const int tid  = threadIdx.x;
  const int lane = tid & 63;
  const int wid  = tid >> 6;            // 0..7
  const int lo   = lane & 15, hi = lane >> 4;

  const int lin = blockIdx.y * gridDim.x + blockIdx.x;
  const int nwg = gridDim.x * gridDim.y;
  const int sw  = (lin & 7) * (nwg >> 3) + (lin >> 3);
  const int n0  = (sw % gridDim.x) * 128;
  const int m0  = (sw / gridDim.x) * 128;

  const int wm = (wid >> 1) * 32;       // 0,32,64,96
  const int wn = (wid & 1) * 64;        // 0,64

  floatx4 acc[2][4] = {};

  const int rr = tid >> 2, qq = tid & 3;

  auto issue = [&](int kt, int buf) {
    async_copy16(A  + (size_t)(m0 + rr) * K + kt + qq * 8, &As[buf][(size_t)tid * 8]);
    async_copy16(Bw + (size_t)(n0 + rr) * K + kt + qq * 8, &Bs[buf][(size_t)tid * 8]);
  };

  issue(0, 0);
  const int nk = K >> 5;
  for (int t = 0; t < nk; ++t) {
    __syncthreads();
    if (t + 1 < nk) issue((t + 1) << 5, (t + 1) & 1);
    const u16* as = As[t & 1];
    const u16* bs = Bs[t & 1];
    svec8 af[2], bfr[4];
    #pragma unroll
    for (int i = 0; i < 2; ++i)
      af[i] = *(const svec8*)&as[(wm + i * 16 + lo) * 32 + hi * 8];
    #pragma unroll
    for (int i = 0; i < 4; ++i)
      bfr[i] = *(const svec8*)&bs[(wn + i * 16 + lo) * 32 + hi * 8];
    #pragma unroll
    for (int mi = 0; mi < 2; ++mi)
      #pragma unroll
      for (int ni = 0; ni < 4; ++ni)
        acc[mi][ni] = __builtin_amdgcn_mfma_f32_16x16x32_bf16(af[mi], bfr[ni], acc[mi][ni], 0, 0, 0);
  }

  #pragma unroll
  for (int mi = 0; mi < 2; ++mi) {
    #pragma unroll
    for (int ni = 0; ni < 4; ++ni) {
      #pragma unroll
      for (int j = 0; j < 4; ++j) {
        int r = m0 + wm + mi * 16 + hi * 4 + j;
        int c = n0 + wn + ni * 16 + lo;
        float v = acc[mi][ni][j] + bias[c];
        if constexpr (EPI == 0) {
          if (c < 256) v *= SCALE_Q;
          outb[(size_t)r * N + c] = f2bf(v);
        } else {
          outb[(size_t)r * N + c] = f2bf(v);
        }
      }
    }
  }
}

// ---------------------------------------------------------------------------
// Fused MLP: out += fc2(gelu(fc1(yb))) + biases, residual in-place on d_out.
// One block = 128 rows, 8 waves, wave = 16 rows. NO barriers:
//  - A (yb rows) loaded once to 32 VGPR.
//  - loop 16 hid-chunks of 64: fc1 MFMA (W1 frags direct from global/L2),
//    exact gelu, bf16 pack into wave-PRIVATE LDS patch (transpose), fc2 MFMA
//    (W2 frags direct from global/L2) accumulating into 16 persistent frags.
//  - epilogue: += bias2 + x2 (read-modify-write f32, full dense rows).
// Weights total 1 MB -> L2-resident; h1 never touches HBM.
// ---------------------------------------------------------------------------
__global__ __launch_bounds__(512)
void mlp_fused(const u16* __restrict__ yb, const u16* __restrict__ w1,
               const float* __restrict__ b1, const u16* __restrict__ w2,
               const float* __restrict__ b2, float* __restrict__ xio)
{
  __shared__ __align__(16) u16 hbuf[8][16 * 72];   // per-wave 16 rows x 64 hid
  const int tid  = threadIdx.x;
  const int lane = tid & 63;
  const int wv   = tid >> 6;
  const int lo   = lane & 15, hi = lane >> 4;
  const int r0   = blockIdx.x * 128 + wv * 16;

  // A fragments: rows r0+lo, full K=256 (8 x svec8 = 32 VGPR), read once
  const u16* arow = yb + (size_t)(r0 + lo) * 256;
  svec8 af[8];
  #pragma unroll
  for (int kk = 0; kk < 8; ++kk)
    af[kk] = *(const svec8*)(arow + kk * 32 + hi * 8);

  u16* myh = &hbuf[wv][0];
  floatx4 oacc[16] = {};

  #pragma unroll 1
  for (int hc = 0; hc < 16; ++hc) {
    const int h0 = hc * 64;
    // ---- fc1: 4 n-frags x 8 kk ----
    floatx4 facc[4];
    #pragma unroll
    for (int nb = 0; nb < 4; ++nb) {
      float bv = b1[h0 + nb * 16 + lo];
      facc[nb] = (floatx4){bv, bv, bv, bv};
    }
    #pragma unroll
    for (int nb = 0; nb < 4; ++nb) {
      const u16* wrow = w1 + (size_t)(h0 + nb * 16 + lo) * 256;
      #pragma unroll
      for (int kk = 0; kk < 8; ++kk) {
        svec8 bfr = *(const svec8*)(wrow + kk * 32 + hi * 8);
        facc[nb] = __builtin_amdgcn_mfma_f32_16x16x32_bf16(af[kk], bfr, facc[nb], 0, 0, 0);
      }
    }
    // ---- gelu + transpose via wave-private LDS ----
    #pragma unroll
    for (int nb = 0; nb < 4; ++nb)
      #pragma unroll
      for (int j = 0; j < 4; ++j) {
        float v  = facc[nb][j];
        float gv = 0.5f * v * (1.0f + erff(v * 0.70710678118654752f));
        myh[(hi * 4 + j) * 72 + nb * 16 + lo] = f2bf(gv);
      }
    // ---- fc2 partial: 2 k-subfrags x 16 n-frags ----
    #pragma unroll
    for (int ks = 0; ks < 2; ++ks) {
      svec8 pa = *(const svec8*)&myh[lo * 72 + ks * 32 + hi * 8];
      #pragma unroll
      for (int nt = 0; nt < 16; ++nt) {
        const u16* w2p = w2 + (size_t)(nt * 16 + lo) * 1024 + h0 + ks * 32 + hi * 8;
        svec8 bfr = *(const svec8*)w2p;
        oacc[nt] = __builtin_amdgcn_mfma_f32_16x16x32_bf16(pa, bfr, oacc[nt], 0, 0, 0);
      }
    }
  }

  // ---- epilogue: += bias2, residual in place ----
  #pragma unroll
  for (int nt = 0; nt < 16; ++nt) {
    int c = nt * 16 + lo;
    float bv = b2[c];
    #pragma unroll
    for (int j = 0; j < 4; ++j) {
      size_t o = (size_t)(r0 + hi * 4 + j) * 256 + c;
      xio[o] = xio[o] + oacc[nt][j] + bv;
    }
  }
}

// ---------------------------------------------------------------------------
// Attention: one block per (window, head), 4 waves; wave wv owns queries
// [wv*16, wv*16+16). Logits = (I+T) @ S_bf16 (MFMA, acc init = rpbm which
// folds rpb + pe_b + shift mask). In-register softmax. PV via LDS.
// ---------------------------------------------------------------------------
__global__ __launch_bounds__(256)
void attn2(const u16* __restrict__ qkv, const float* __restrict__ rpbm,
           const u16* __restrict__ mconv, u16* __restrict__ outb)
{
  __shared__ __align__(16) u16 Ks[64 * 40];
  __shared__ __align__(16) u16 Vt[32 * 72];
  __shared__ __align__(16) u16 ST[64 * 72];
  __shared__ __align__(16) u16 Pm[64 * 72];

  const int tid  = threadIdx.x;
  const int lane = tid & 63, wv = tid >> 6;
  const int lo   = lane & 15, hi = lane >> 4;
  const int wId  = blockIdx.x >> 3;
  const int h    = blockIdx.x & 7;
  const int wi   = wId & 255;
  const int cls  = (((wi >> 4) == 15) ? 2 : 0) + (((wi & 15) == 15) ? 1 : 0);
  const int m0   = wv * 16;

  { // stage k and V^T
    int r = tid >> 2, ch = tid & 3;
    const size_t base = (size_t)(wId * 64 + r) * 768 + h * 32 + ch * 8;
    *(ivec4*)&Ks[r * 40 + ch * 8] = *(const ivec4*)(qkv + base + 256);
    ivec4 vv = *(const ivec4*)(qkv + base + 512);
    const u16* pv = (const u16*)&vv;
    #pragma unroll
    for (int e = 0; e < 8; ++e) Vt[(ch * 8 + e) * 72 + r] = pv[e];
  }
  __syncthreads();

  { // QK^T (K=32): A = q rows (global), B = k rows (LDS). Write S^T bf16.
    svec8 qa = *(const svec8*)(qkv + (size_t)(wId * 64 + m0 + lo) * 768 + h * 32 + hi * 8);
    floatx4 z = {0.f, 0.f, 0.f, 0.f};
    #pragma unroll
    for (int nb = 0; nb < 4; ++nb) {
      svec8 kb = *(const svec8*)&Ks[(nb * 16 + lo) * 40 + hi * 8];
      floatx4 s = __builtin_amdgcn_mfma_f32_16x16x32_bf16(qa, kb, z, 0, 0, 0);
      #pragma unroll
      for (int jp = 0; jp < 2; ++jp) {
        u32 pk = (u32)f2bf(s[jp * 2]) | ((u32)f2bf(s[jp * 2 + 1]) << 16);
        *(u32*)&ST[(nb * 16 + lo) * 72 + m0 + hi * 4 + jp * 2] = pk;
      }
    }
  }
  __syncthreads();

  floatx4 acc[4];
  { // conv-MFMA: L = (I+T) @ S, acc init = rpbm
    const float* rb = rpbm + (size_t)(cls * 8 + h) * 4096;
    #pragma unroll
    for (int nb = 0; nb < 4; ++nb)
      #pragma unroll
      for (int j = 0; j < 4; ++j)
        acc[nb][j] = rb[(m0 + hi * 4 + j) * 64 + nb * 16 + lo];
    svec8 mf0 = *(const svec8*)(mconv + ((h * 64 + m0 + lo) * 64 + hi * 8));
    svec8 mf1 = *(const svec8*)(mconv + ((h * 64 + m0 + lo) * 64 + 32 + hi * 8));
    #pragma unroll
    for (int nb = 0; nb < 4; ++nb) {
      svec8 st0 = *(const svec8*)&ST[(nb * 16 + lo) * 72 + hi * 8];
      svec8 st1 = *(const svec8*)&ST[(nb * 16 + lo) * 72 + 32 + hi * 8];
      acc[nb] = __builtin_amdgcn_mfma_f32_16x16x32_bf16(mf0, st0, acc[nb], 0, 0, 0);
      acc[nb] = __builtin_amdgcn_mfma_f32_16x16x32_bf16(mf1, st1, acc[nb], 0, 0, 0);
    }
  }

  { // in-register softmax over keys
    float ev[4][4], inv[4];
    #pragma unroll
    for (int j = 0; j < 4; ++j) {
      float m_ = fmaxf(fmaxf(acc[0][j], acc[1][j]), fmaxf(acc[2][j], acc[3][j]));
      m_ = fmaxf(m_, __shfl_xor(m_, 1)); m_ = fmaxf(m_, __shfl_xor(m_, 2));
      m_ = fmaxf(m_, __shfl_xor(m_, 4)); m_ = fmaxf(m_, __shfl_xor(m_, 8));
      #pragma unroll
      for (int nb = 0; nb < 4; ++nb) ev[nb][j] = __expf(acc[nb][j] - m_);
      float s_ = ev[0][j] + ev[1][j] + ev[2][j] + ev[3][j];
      s_ += __shfl_xor(s_, 1); s_ += __shfl_xor(s_, 2);
      s_ += __shfl_xor(s_, 4); s_ += __shfl_xor(s_, 8);
      inv[j] = __builtin_amdgcn_rcpf(s_);
    }
    #pragma unroll
    for (int nb = 0; nb < 4; ++nb)
      #pragma unroll
      for (int j = 0; j < 4; ++j)
        Pm[(m0 + hi * 4 + j) * 72 + nb * 16 + lo] = f2bf(ev[nb][j] * inv[j]);
  }
  __syncthreads();

  { // PV
    floatx4 oacc[2] = {};
    #pragma unroll
    for (int ks = 0; ks < 2; ++ks) {
      svec8 pa = *(const svec8*)&Pm[(m0 + lo) * 72 + ks * 32 + hi * 8];
      #pragma unroll
      for (int nb = 0; nb < 2; ++nb) {
        svec8 vb = *(const svec8*)&Vt[(nb * 16 + lo) * 72 + ks * 32 + hi * 8];
        oacc[nb] = __builtin_amdgcn_mfma_f32_16x16x32_bf16(pa, vb, oacc[nb], 0, 0, 0);
      }
    }
    #pragma unroll
    for (int nb = 0; nb < 2; ++nb)
      #pragma unroll
      for (int j = 0; j < 4; ++j)
        outb[(size_t)(wId * 64 + m0 + hi * 4 + j) * 256 + h * 32 + nb * 16 + lo] = f2bf(oacc[nb][j]);
  }
}

// ---------------------------------------------------------------------------
extern "C" void kernel_launch(void* const* d_in, const int* in_sizes, int n_in,
                              void* d_out, int out_size, void* d_ws, size_t ws_size,
                              hipStream_t stream)
{
  const float* x      = (const float*)d_in[0];
  const float* n1g    = (const float*)d_in[1];
  const float* n1b    = (const float*)d_in[2];
  const float* qkv_w  = (const float*)d_in[3];
  const float* qkv_b  = (const float*)d_in[4];
  const float* rpb    = (const float*)d_in[5];
  const float* pe_w   = (const float*)d_in[6];
  const float* pe_b   = (const float*)d_in[7];
  const float* proj_w = (const float*)d_in[8];
  const float* proj_b = (const float*)d_in[9];
  const float* n2g    = (const float*)d_in[10];
  const float* n2b    = (const float*)d_in[11];
  const float* fc1_w  = (const float*)d_in[12];
  const float* fc1_b  = (const float*)d_in[13];
  const float* fc2_w  = (const float*)d_in[14];
  const float* fc2_b  = (const float*)d_in[15];
  float* outf = (float*)d_out;

  char* ws = (char*)d_ws;
  u16* qkvb    = (u16*)ws;                          // [0,192M) phase1
  u16* winb    = (u16*)(ws + (192ull << 20));       // [192,256M) phase1
  u16* yb      = (u16*)ws;                          // [0,64M)   phase2
  u16* projoutb= (u16*)(ws + (64ull << 20));        // [64,128M) phase2
  u16* fc1wb   = (u16*)(ws + (192ull << 20));       // 512K (after proj reads winb)
  u16* fc2wb   = (u16*)(ws + (192ull << 20) + (1ull << 19));

  // d_out scratch (dead until resid_ln2)
  u16*   qkvwb  = (u16*)d_out;                              // 384K
  float* rpbmT  = (float*)((char*)d_out + (1ull << 19));    // 512K
  u16*   mconvT = (u16*)((char*)d_out + (1ull << 20));      // 64K
  u16*   projwb = (u16*)((char*)d_out + (1ull << 20) + (1ull << 18)); // 128K

  // setup
  cvt_kernel<<<192, 256, 0, stream>>>(qkv_w, qkvwb, 196608);
  rpbm_kernel<<<512, 256, 0, stream>>>(rpb, pe_b, rpbmT);
  mconv_kernel<<<128, 256, 0, stream>>>(pe_w, mconvT);
  cvt_kernel<<<64, 256, 0, stream>>>(proj_w, projwb, 65536);

  // 1) LN1 + shift + window partition
  ln_kernel<1><<<32768, 256, 0, stream>>>(x, n1g, n1b, winb);
  // 2) QKV GEMM
  gemm4<0><<<dim3(6, 1024), 512, 0, stream>>>(winb, qkvwb, qkv_b, qkvb, nullptr, nullptr, 768, 256, 0);
  // 3) attention -> winb (overwrites LN1 output)
  attn2<<<16384, 256, 0, stream>>>(qkvb, rpbmT, mconvT, winb);
  // 4) proj GEMM -> projout bf16 (linear, window order)
  gemm4<1><<<dim3(2, 1024), 512, 0, stream>>>(winb, projwb, proj_b, projoutb, nullptr, nullptr, 256, 256, 0);
  // 4b) convert fc weights (winb dead after proj)
  cvt_kernel<<<256, 256, 0, stream>>>(fc1_w, fc1wb, 262144);
  cvt_kernel<<<256, 256, 0, stream>>>(fc2_w, fc2wb, 262144);
  // 5) fused unshift+residual+LN2: x2 -> d_out, yb -> ws
  resid_ln2<<<32768, 256, 0, stream>>>(x, projoutb, n2g, n2b, outf, yb);
  // 6) fused MLP (fc1 + gelu + fc2 + residual), in-place on d_out
  mlp_fused<<<1024, 512, 0, stream>>>(yb, fc1wb, fc1_b, fc2wb, fc2_b, outf);
}

// Round 7
// 874.692 us; speedup vs baseline: 2.7586x; 1.7548x over previous
//
#include <hip/hip_runtime.h>

// ---------------------------------------------------------------------------
// Swin block on MI355X. B=8, H=W=128, C=256, NH=8, HD=32, WS=8, SS=4, N=64,
// NW=256, tokens M=131072, HID=1024.
// ws (256 MiB):
//   phase1: qkvb [0,192M) | winb [192,256M)
//   phase2 (post-attn): yb [0,64M) | h1b [64,192M) | projout [128,192M) (dead
//           before h1b written) | fc1wb/fc2wb [192,256M) (after proj reads winb)
// d_out doubles as scratch until resid_ln2: qkvwb [0,384K), rpbm [512K,1M),
//   mconv [1M,1M+64K), projwb [1.25M,+128K)
// ---------------------------------------------------------------------------

typedef unsigned short u16;
typedef unsigned int   u32;
typedef __attribute__((ext_vector_type(4))) int   ivec4;
typedef __attribute__((ext_vector_type(4))) float fvec4;
typedef __attribute__((ext_vector_type(8))) short svec8;
typedef __attribute__((ext_vector_type(4))) unsigned short usvec4;
typedef __attribute__((ext_vector_type(4))) float floatx4;

#define SCALE_Q 0.17677669529663687f

__device__ __forceinline__ u16 f2bf(float f) {
  union { float f; u32 u; } v; v.f = f;
  u32 r = v.u + 0x7FFFu + ((v.u >> 16) & 1u);
  return (u16)(r >> 16);
}
__device__ __forceinline__ float bf2f(u16 h) {
  union { u32 u; float f; } v; v.u = ((u32)h) << 16; return v.f;
}

__device__ __forceinline__ void async_copy16(const u16* g, u16* l) {
  __builtin_amdgcn_global_load_lds(
      (const __attribute__((address_space(1))) u32*)g,
      (__attribute__((address_space(3))) u32*)l, 16, 0, 0);
}

// ---------------------------------------------------------------------------
// LN1: wave per token (4 tokens/block), float4/lane, shuffle-only reduce.
// SHIFT=1: token order = shifted window partition (gather read of x).
// ---------------------------------------------------------------------------
template<int SHIFT>
__global__ __launch_bounds__(256)
void ln_kernel(const float* __restrict__ x, const float* __restrict__ g,
               const float* __restrict__ b, u16* __restrict__ out)
{
  const int t    = blockIdx.x * 4 + (threadIdx.x >> 6);
  const int lane = threadIdx.x & 63;
  const int c    = lane * 4;
  size_t src;
  if constexpr (SHIFT) {
    int w  = t >> 6, tk = t & 63;
    int bi = w >> 8, wi = w & 255;
    int hr = ((wi >> 4) << 3) + (tk >> 3);
    int wr = ((wi & 15) << 3) + (tk & 7);
    int ho = (hr + 4) & 127, wo = (wr + 4) & 127;
    src = ((size_t)bi * 16384 + (size_t)ho * 128 + wo) * 256 + c;
  } else {
    src = (size_t)t * 256 + c;
  }
  fvec4 v = *(const fvec4*)(x + src);
  float s  = v.x + v.y + v.z + v.w;
  float s2 = v.x * v.x + v.y * v.y + v.z * v.z + v.w * v.w;
  #pragma unroll
  for (int o = 32; o > 0; o >>= 1) { s += __shfl_xor(s, o); s2 += __shfl_xor(s2, o); }
  float mu  = s * (1.0f / 256.0f);
  float var = s2 * (1.0f / 256.0f) - mu * mu;
  float inv = rsqrtf(var + 1e-5f);
  fvec4 gg = *(const fvec4*)(g + c);
  fvec4 bb = *(const fvec4*)(b + c);
  usvec4 o4;
  o4[0] = f2bf((v.x - mu) * inv * gg.x + bb.x);
  o4[1] = f2bf((v.y - mu) * inv * gg.y + bb.y);
  o4[2] = f2bf((v.z - mu) * inv * gg.z + bb.z);
  o4[3] = f2bf((v.w - mu) * inv * gg.w + bb.w);
  *(usvec4*)(out + (size_t)t * 256 + c) = o4;
}

// ---------------------------------------------------------------------------
// resid_ln2: wave per pixel P (row-major). x2 = x + permute(proj_out);
// write x2 (f32, d_out) and LN2(x2) (bf16, yb).
// ---------------------------------------------------------------------------
__global__ __launch_bounds__(256)
void resid_ln2(const float* __restrict__ x, const u16* __restrict__ projout,
               const float* __restrict__ g, const float* __restrict__ b,
               float* __restrict__ x2, u16* __restrict__ yb)
{
  const int P    = blockIdx.x * 4 + (threadIdx.x >> 6);
  const int lane = threadIdx.x & 63;
  const int c    = lane * 4;
  const int bi = P >> 14, ho = (P >> 7) & 127, wo = P & 127;
  const int hr = (ho + 124) & 127, wr = (wo + 124) & 127;
  const int token = (((bi << 8) + ((hr >> 3) << 4) + (wr >> 3)) << 6)
                    + ((hr & 7) << 3) + (wr & 7);
  fvec4 xv = *(const fvec4*)(x + (size_t)P * 256 + c);
  usvec4 pv = *(const usvec4*)(projout + (size_t)token * 256 + c);
  fvec4 v;
  v.x = xv.x + bf2f(pv[0]); v.y = xv.y + bf2f(pv[1]);
  v.z = xv.z + bf2f(pv[2]); v.w = xv.w + bf2f(pv[3]);
  *(fvec4*)(x2 + (size_t)P * 256 + c) = v;
  float s  = v.x + v.y + v.z + v.w;
  float s2 = v.x * v.x + v.y * v.y + v.z * v.z + v.w * v.w;
  #pragma unroll
  for (int o = 32; o > 0; o >>= 1) { s += __shfl_xor(s, o); s2 += __shfl_xor(s2, o); }
  float mu  = s * (1.0f / 256.0f);
  float var = s2 * (1.0f / 256.0f) - mu * mu;
  float inv = rsqrtf(var + 1e-5f);
  fvec4 gg = *(const fvec4*)(g + c);
  fvec4 bb = *(const fvec4*)(b + c);
  usvec4 o4;
  o4[0] = f2bf((v.x - mu) * inv * gg.x + bb.x);
  o4[1] = f2bf((v.y - mu) * inv * gg.y + bb.y);
  o4[2] = f2bf((v.z - mu) * inv * gg.z + bb.z);
  o4[3] = f2bf((v.w - mu) * inv * gg.w + bb.w);
  *(usvec4*)(yb + (size_t)P * 256 + c) = o4;
}

// ---------------------------------------------------------------------------
// Small setup kernels
// ---------------------------------------------------------------------------
__global__ __launch_bounds__(256)
void cvt_kernel(const float* __restrict__ src, u16* __restrict__ dst, int n) {
  int i = (blockIdx.x * 256 + threadIdx.x) * 4;
  if (i < n) {
    fvec4 v = *(const fvec4*)(src + i);
    usvec4 o; o[0] = f2bf(v.x); o[1] = f2bf(v.y); o[2] = f2bf(v.z); o[3] = f2bf(v.w);
    *(usvec4*)(dst + i) = o;
  }
}

// rpbm[cls][h][n][m] = rpb[relidx(n,m)][h] + pe_b[h] + mask(cls,n,m)
__global__ __launch_bounds__(256)
void rpbm_kernel(const float* __restrict__ rpb, const float* __restrict__ pe_b,
                 float* __restrict__ out) {
  int idx = blockIdx.x * 256 + threadIdx.x;          // 131072
  int m = idx & 63, n = (idx >> 6) & 63, hh = (idx >> 12) & 7, cls = idx >> 15;
  int dy = (n >> 3) - (m >> 3) + 7, dx = (n & 7) - (m & 7) + 7;
  float v = rpb[(dy * 15 + dx) * 8 + hh] + pe_b[hh];
  int lastR = cls >> 1, lastC = cls & 1;
  int rn = lastR ? (((n >> 3) < 4) ? 1 : 2) : 0;
  int cn = lastC ? (((n & 7) < 4) ? 1 : 2) : 0;
  int rm = lastR ? (((m >> 3) < 4) ? 1 : 2) : 0;
  int cm = lastC ? (((m & 7) < 4) ? 1 : 2) : 0;
  if (rn * 3 + cn != rm * 3 + cm) v -= 100.0f;
  out[idx] = v;
}

// mconv[h][n][nn] = (n==nn) + (|nn-n|<=7 ? pe_w[h][nn-n+7] : 0), bf16
__global__ __launch_bounds__(256)
void mconv_kernel(const float* __restrict__ pe_w, u16* __restrict__ out) {
  int idx = blockIdx.x * 256 + threadIdx.x;          // 32768
  int nn = idx & 63, n = (idx >> 6) & 63, hh = idx >> 12;
  int d = nn - n;
  float v = (d == 0) ? 1.0f : 0.0f;
  if (d >= -7 && d <= 7) v += pe_w[hh * 15 + d + 7];
  out[idx] = f2bf(v);
}

// ---------------------------------------------------------------------------
// GEMM v5: round-4 gemm4 + DEPTH-4 LDS ring with COUNTED vmcnt (T4).
// C[M,N] = A[M,K]bf16 * W[N,K]bf16^T. 128x128 tile, BK=32, 8 waves,
// wave tile 32x64. Prologue issues 3 tiles; each iter: wait slot t only
// (vmcnt(4) = slots t+1,t+2 still in flight), barrier, issue slot t+3,
// ds_read + MFMA. Loads get ~3 compute phases of latency cover vs 1.
// Race-safe: slot (t+3)&3 == (t-1)&3 overwrite happens after the iter-t
// barrier, by which point every wave consumed its iter-(t-1) ds_reads.
// EPI: 0 qkv (+bias, scale q) | 1 proj (+bias) | 2 fc1 (+bias, exact gelu)
//      3 fc2 (+bias + residual f32 in d_out)
// ---------------------------------------------------------------------------
template<int EPI>
__global__ __launch_bounds__(512, 4)
void gemm5(const u16* __restrict__ A, const u16* __restrict__ Bw,
           const float* __restrict__ bias, u16* outb, float* outf,
           const float* __restrict__ extra, int N, int K, int row0)
{
  __shared__ __align__(16) u16 As[4][128 * 32];   // 32 KB
  __shared__ __align__(16) u16 Bs[4][128 * 32];   // 32 KB
  const int tid  = threadIdx.x;
  const int lane = tid & 63;
  const int wid  = tid >> 6;            // 0..7
  const int lo   = lane & 15, hi = lane >> 4;

  // XCD swizzle: nwg % 8 == 0 for all our grids -> bijective
  const int lin = blockIdx.y * gridDim.x + blockIdx.x;
  const int nwg = gridDim.x * gridDim.y;
  const int sw  = (lin & 7) * (nwg >> 3) + (lin >> 3);
  const int n0  = (sw % gridDim.x) * 128;
  const int m0  = (sw / gridDim.x) * 128;

  const int wm = (wid >> 1) * 32;       // 0,32,64,96
  const int wn = (wid & 1) * 64;        // 0,64

  floatx4 acc[2][4] = {};

  const int rr = tid >> 2, qq = tid & 3;

  auto issue = [&](int t) {
    const int kt  = t << 5;
    const int buf = t & 3;
    async_copy16(A  + (size_t)(m0 + rr) * K + kt + qq * 8, &As[buf][(size_t)tid * 8]);
    async_copy16(Bw + (size_t)(n0 + rr) * K + kt + qq * 8, &Bs[buf][(size_t)tid * 8]);
  };

  issue(0); issue(1); issue(2);          // 6 loads in flight
  const int nk = K >> 5;                 // >= 8 for all our shapes
  for (int t = 0; t < nk; ++t) {
    const int rem = nk - 1 - t;
    if (rem >= 2)      asm volatile("s_waitcnt vmcnt(4)" ::: "memory");
    else if (rem == 1) asm volatile("s_waitcnt vmcnt(2)" ::: "memory");
    else               asm volatile("s_waitcnt vmcnt(0)" ::: "memory");
    __builtin_amdgcn_s_barrier();
    __builtin_amdgcn_sched_barrier(0);
    if (t + 3 < nk) issue(t + 3);
    const u16* as = As[t & 3];
    const u16* bs = Bs[t & 3];
    svec8 af[2], bfr[4];
    #pragma unroll
    for (int i = 0; i < 2; ++i)
      af[i] = *(const svec8*)&as[(wm + i * 16 + lo) * 32 + hi * 8];
    #pragma unroll
    for (int i = 0; i < 4; ++i)
      bfr[i] = *(const svec8*)&bs[(wn + i * 16 + lo) * 32 + hi * 8];
    #pragma unroll
    for (int mi = 0; mi < 2; ++mi)
      #pragma unroll
      for (int ni = 0; ni < 4; ++ni)
        acc[mi][ni] = __builtin_amdgcn_mfma_f32_16x16x32_bf16(af[mi], bfr[ni], acc[mi][ni], 0, 0, 0);
  }

  #pragma unroll
  for (int mi = 0; mi < 2; ++mi) {
    #pragma unroll
    for (int ni = 0; ni < 4; ++ni) {
      #pragma unroll
      for (int j = 0; j < 4; ++j) {
        int r = m0 + wm + mi * 16 + hi * 4 + j;
        int c = n0 + wn + ni * 16 + lo;
        float v = acc[mi][ni][j] + bias[c];
        if constexpr (EPI == 0) {
          if (c < 256) v *= SCALE_Q;
          outb[(size_t)r * N + c] = f2bf(v);
        } else if constexpr (EPI == 1) {
          outb[(size_t)r * N + c] = f2bf(v);
        } else if constexpr (EPI == 2) {
          float gv = 0.5f * v * (1.0f + erff(v * 0.70710678118654752f));
          outb[(size_t)r * N + c] = f2bf(gv);
        } else {
          size_t o = (size_t)(row0 + r) * N + c;
          outf[o] = extra[o] + v;
        }
      }
    }
  }
}

// ---------------------------------------------------------------------------
// Attention: one block per (window, head), 4 waves; wave wv owns queries
// [wv*16, wv*16+16). Logits = (I+T) @ S_bf16 (MFMA, acc init = rpbm which
// folds rpb + pe_b + shift mask). In-register softmax. PV via LDS.
// ---------------------------------------------------------------------------
__global__ __launch_bounds__(256)
void attn2(const u16* __restrict__ qkv, const float* __restrict__ rpbm,
           const u16* __restrict__ mconv, u16* __restrict__ outb)
{
  __shared__ __align__(16) u16 Ks[64 * 40];
  __shared__ __align__(16) u16 Vt[32 * 72];
  __shared__ __align__(16) u16 ST[64 * 72];
  __shared__ __align__(16) u16 Pm[64 * 72];

  const int tid  = threadIdx.x;
  const int lane = tid & 63, wv = tid >> 6;
  const int lo   = lane & 15, hi = lane >> 4;
  const int wId  = blockIdx.x >> 3;
  const int h    = blockIdx.x & 7;
  const int wi   = wId & 255;
  const int cls  = (((wi >> 4) == 15) ? 2 : 0) + (((wi & 15) == 15) ? 1 : 0);
  const int m0   = wv * 16;

  { // stage k and V^T
    int r = tid >> 2, ch = tid & 3;
    const size_t base = (size_t)(wId * 64 + r) * 768 + h * 32 + ch * 8;
    *(ivec4*)&Ks[r * 40 + ch * 8] = *(const ivec4*)(qkv + base + 256);
    ivec4 vv = *(const ivec4*)(qkv + base + 512);
    const u16* pv = (const u16*)&vv;
    #pragma unroll
    for (int e = 0; e < 8; ++e) Vt[(ch * 8 + e) * 72 + r] = pv[e];
  }
  __syncthreads();

  { // QK^T (K=32): A = q rows (global), B = k rows (LDS). Write S^T bf16.
    svec8 qa = *(const svec8*)(qkv + (size_t)(wId * 64 + m0 + lo) * 768 + h * 32 + hi * 8);
    floatx4 z = {0.f, 0.f, 0.f, 0.f};
    #pragma unroll
    for (int nb = 0; nb < 4; ++nb) {
      svec8 kb = *(const svec8*)&Ks[(nb * 16 + lo) * 40 + hi * 8];
      floatx4 s = __builtin_amdgcn_mfma_f32_16x16x32_bf16(qa, kb, z, 0, 0, 0);
      #pragma unroll
      for (int jp = 0; jp < 2; ++jp) {
        u32 pk = (u32)f2bf(s[jp * 2]) | ((u32)f2bf(s[jp * 2 + 1]) << 16);
        *(u32*)&ST[(nb * 16 + lo) * 72 + m0 + hi * 4 + jp * 2] = pk;
      }
    }
  }
  __syncthreads();

  floatx4 acc[4];
  { // conv-MFMA: L = (I+T) @ S, acc init = rpbm
    const float* rb = rpbm + (size_t)(cls * 8 + h) * 4096;
    #pragma unroll
    for (int nb = 0; nb < 4; ++nb)
      #pragma unroll
      for (int j = 0; j < 4; ++j)
        acc[nb][j] = rb[(m0 + hi * 4 + j) * 64 + nb * 16 + lo];
    svec8 mf0 = *(const svec8*)(mconv + ((h * 64 + m0 + lo) * 64 + hi * 8));
    svec8 mf1 = *(const svec8*)(mconv + ((h * 64 + m0 + lo) * 64 + 32 + hi * 8));
    #pragma unroll
    for (int nb = 0; nb < 4; ++nb) {
      svec8 st0 = *(const svec8*)&ST[(nb * 16 + lo) * 72 + hi * 8];
      svec8 st1 = *(const svec8*)&ST[(nb * 16 + lo) * 72 + 32 + hi * 8];
      acc[nb] = __builtin_amdgcn_mfma_f32_16x16x32_bf16(mf0, st0, acc[nb], 0, 0, 0);
      acc[nb] = __builtin_amdgcn_mfma_f32_16x16x32_bf16(mf1, st1, acc[nb], 0, 0, 0);
    }
  }

  { // in-register softmax over keys
    float ev[4][4], inv[4];
    #pragma unroll
    for (int j = 0; j < 4; ++j) {
      float m_ = fmaxf(fmaxf(acc[0][j], acc[1][j]), fmaxf(acc[2][j], acc[3][j]));
      m_ = fmaxf(m_, __shfl_xor(m_, 1)); m_ = fmaxf(m_, __shfl_xor(m_, 2));
      m_ = fmaxf(m_, __shfl_xor(m_, 4)); m_ = fmaxf(m_, __shfl_xor(m_, 8));
      #pragma unroll
      for (int nb = 0; nb < 4; ++nb) ev[nb][j] = __expf(acc[nb][j] - m_);
      float s_ = ev[0][j] + ev[1][j] + ev[2][j] + ev[3][j];
      s_ += __shfl_xor(s_, 1); s_ += __shfl_xor(s_, 2);
      s_ += __shfl_xor(s_, 4); s_ += __shfl_xor(s_, 8);
      inv[j] = __builtin_amdgcn_rcpf(s_);
    }
    #pragma unroll
    for (int nb = 0; nb < 4; ++nb)
      #pragma unroll
      for (int j = 0; j < 4; ++j)
        Pm[(m0 + hi * 4 + j) * 72 + nb * 16 + lo] = f2bf(ev[nb][j] * inv[j]);
  }
  __syncthreads();

  { // PV
    floatx4 oacc[2] = {};
    #pragma unroll
    for (int ks = 0; ks < 2; ++ks) {
      svec8 pa = *(const svec8*)&Pm[(m0 + lo) * 72 + ks * 32 + hi * 8];
      #pragma unroll
      for (int nb = 0; nb < 2; ++nb) {
        svec8 vb = *(const svec8*)&Vt[(nb * 16 + lo) * 72 + ks * 32 + hi * 8];
        oacc[nb] = __builtin_amdgcn_mfma_f32_16x16x32_bf16(pa, vb, oacc[nb], 0, 0, 0);
      }
    }
    #pragma unroll
    for (int nb = 0; nb < 2; ++nb)
      #pragma unroll
      for (int j = 0; j < 4; ++j)
        outb[(size_t)(wId * 64 + m0 + hi * 4 + j) * 256 + h * 32 + nb * 16 + lo] = f2bf(oacc[nb][j]);
  }
}

// ---------------------------------------------------------------------------
extern "C" void kernel_launch(void* const* d_in, const int* in_sizes, int n_in,
                              void* d_out, int out_size, void* d_ws, size_t ws_size,
                              hipStream_t stream)
{
  const float* x      = (const float*)d_in[0];
  const float* n1g    = (const float*)d_in[1];
  const float* n1b    = (const float*)d_in[2];
  const float* qkv_w  = (const float*)d_in[3];
  const float* qkv_b  = (const float*)d_in[4];
  const float* rpb    = (const float*)d_in[5];
  const float* pe_w   = (const float*)d_in[6];
  const float* pe_b   = (const float*)d_in[7];
  const float* proj_w = (const float*)d_in[8];
  const float* proj_b = (const float*)d_in[9];
  const float* n2g    = (const float*)d_in[10];
  const float* n2b    = (const float*)d_in[11];
  const float* fc1_w  = (const float*)d_in[12];
  const float* fc1_b  = (const float*)d_in[13];
  const float* fc2_w  = (const float*)d_in[14];
  const float* fc2_b  = (const float*)d_in[15];
  float* outf = (float*)d_out;

  char* ws = (char*)d_ws;
  u16* qkvb    = (u16*)ws;                          // [0,192M) phase1
  u16* winb    = (u16*)(ws + (192ull << 20));       // [192,256M) phase1
  u16* yb      = (u16*)ws;                          // [0,64M)   phase2
  u16* h1b     = (u16*)(ws + (64ull << 20));        // [64,192M) phase2
  u16* projoutb= (u16*)(ws + (128ull << 20));       // [128,192M) (dead before h1 use)
  u16* fc1wb   = (u16*)(ws + (192ull << 20));       // 512K (after proj reads winb)
  u16* fc2wb   = (u16*)(ws + (192ull << 20) + (1ull << 19));

  // d_out scratch (dead until resid_ln2)
  u16*   qkvwb  = (u16*)d_out;                              // 384K
  float* rpbmT  = (float*)((char*)d_out + (1ull << 19));    // 512K
  u16*   mconvT = (u16*)((char*)d_out + (1ull << 20));      // 64K
  u16*   projwb = (u16*)((char*)d_out + (1ull << 20) + (1ull << 18)); // 128K

  // setup
  cvt_kernel<<<192, 256, 0, stream>>>(qkv_w, qkvwb, 196608);
  rpbm_kernel<<<512, 256, 0, stream>>>(rpb, pe_b, rpbmT);
  mconv_kernel<<<128, 256, 0, stream>>>(pe_w, mconvT);
  cvt_kernel<<<64, 256, 0, stream>>>(proj_w, projwb, 65536);

  // 1) LN1 + shift + window partition
  ln_kernel<1><<<32768, 256, 0, stream>>>(x, n1g, n1b, winb);
  // 2) QKV GEMM
  gemm5<0><<<dim3(6, 1024), 512, 0, stream>>>(winb, qkvwb, qkv_b, qkvb, nullptr, nullptr, 768, 256, 0);
  // 3) attention -> winb (overwrites LN1 output)
  attn2<<<16384, 256, 0, stream>>>(qkvb, rpbmT, mconvT, winb);
  // 4) proj GEMM -> projout bf16 (linear, window order)
  gemm5<1><<<dim3(2, 1024), 512, 0, stream>>>(winb, projwb, proj_b, projoutb, nullptr, nullptr, 256, 256, 0);
  // 4b) convert fc weights (winb dead after proj)
  cvt_kernel<<<256, 256, 0, stream>>>(fc1_w, fc1wb, 262144);
  cvt_kernel<<<256, 256, 0, stream>>>(fc2_w, fc2wb, 262144);
  // 5) fused unshift+residual+LN2: x2 -> d_out, yb -> ws
  resid_ln2<<<32768, 256, 0, stream>>>(x, projoutb, n2g, n2b, outf, yb);
  // 6) MLP in two M-halves (h1 = 128 MiB in [64,192M))
  for (int half = 0; half < 2; ++half) {
    int r0 = half * 65536;
    gemm5<2><<<dim3(8, 512), 512, 0, stream>>>(yb + (size_t)r0 * 256, fc1wb, fc1_b, h1b, nullptr, nullptr, 1024, 256, 0);
    gemm5<3><<<dim3(2, 512), 512, 0, stream>>>(h1b, fc2wb, fc2_b, nullptr, outf, outf, 256, 1024, r0);
  }
}